// Round 1
// baseline (1364.994 us; speedup 1.0000x reference)
//
#include <hip/hip_runtime.h>
#include <hip/hip_bf16.h>

// ---------------------------------------------------------------------------
// HybridAutoEncoder on MI355X.
//
// Pipeline (B=2048, D=4096, H1=2048, H2=1024, L=12):
//   h1 = relu(x @ W1^T + b1)          GEMM 2048x2048x4096
//   h2 = relu(h1 @ W2^T + b2)         GEMM 2048x1024x2048
//   z  = h2 @ W3^T + b3               (fused into quantum kernel)
//   qz[b,q] = prod_{j in S_q} cos(z[b,j] + qp[j])   (analytic quantum latent)
//   h3 = relu(qz @ dW1^T + db1)       GEMM 2048x1024x12
//   h4 = relu(h3 @ dW2^T + db2)       GEMM 2048x2048x1024
//   out= h4 @ dW3^T + db3             GEMM 2048x4096x2048
//
// Quantum latent derivation: RX on |0> -> product state, per-qubit
// P(bit=1)=sin^2(theta/2). CNOT(c,t) permutes basis states via t ^= c.
// <Z_q> of final qubit q = E[(-1)^{xor of initial bits in S_q}]
//                        = prod_{j in S_q} (cos^2 - sin^2) = prod cos(theta_j).
// S_q computed by replaying the 24 CNOTs on index sets (masks below).
// ---------------------------------------------------------------------------

#define TM 64
#define TN 64
#define TK 16

template <bool RELU>
__global__ __launch_bounds__(256) void gemm_bias_act(
    const float* __restrict__ A,   // M x K row-major
    const float* __restrict__ W,   // N x K row-major (out_features x in_features)
    const float* __restrict__ bias,// N
    float* __restrict__ C,         // M x N
    int M, int N, int K)
{
    __shared__ float As[TK][TM + 4];  // +4 pad keeps 16B alignment of rows
    __shared__ float Ws[TK][TN + 4];

    const int bn = blockIdx.x * TN;
    const int bm = blockIdx.y * TM;
    const int t  = threadIdx.x;       // 0..255
    const int tx = t & 15;            // 16 cols of threads
    const int ty = t >> 4;            // 16 rows of threads

    float acc[4][4] = {};

    for (int k0 = 0; k0 < K; k0 += TK) {
        // Stage A tile: 64 rows x 16 k (1024 elems, 4 per thread)
        #pragma unroll
        for (int i = 0; i < 4; ++i) {
            int idx = t + i * 256;
            int mm  = idx >> 4;
            int kk  = idx & 15;
            float v = 0.f;
            if (k0 + kk < K) v = A[(size_t)(bm + mm) * K + k0 + kk];
            As[kk][mm] = v;
        }
        // Stage W tile: 64 n-rows x 16 k
        #pragma unroll
        for (int i = 0; i < 4; ++i) {
            int idx = t + i * 256;
            int nn  = idx >> 4;
            int kk  = idx & 15;
            float v = 0.f;
            if (k0 + kk < K) v = W[(size_t)(bn + nn) * K + k0 + kk];
            Ws[kk][nn] = v;
        }
        __syncthreads();

        #pragma unroll
        for (int kk = 0; kk < TK; ++kk) {
            const float4 a4 = *reinterpret_cast<const float4*>(&As[kk][ty * 4]);
            const float4 b4 = *reinterpret_cast<const float4*>(&Ws[kk][tx * 4]);
            const float a[4] = {a4.x, a4.y, a4.z, a4.w};
            const float b[4] = {b4.x, b4.y, b4.z, b4.w};
            #pragma unroll
            for (int i = 0; i < 4; ++i)
                #pragma unroll
                for (int j = 0; j < 4; ++j)
                    acc[i][j] = fmaf(a[i], b[j], acc[i][j]);
        }
        __syncthreads();
    }

    #pragma unroll
    for (int i = 0; i < 4; ++i) {
        const int m = bm + ty * 4 + i;
        #pragma unroll
        for (int j = 0; j < 4; ++j) {
            const int n = bn + tx * 4 + j;
            float v = acc[i][j] + bias[n];
            if (RELU) v = fmaxf(v, 0.f);
            C[(size_t)m * N + n] = v;
        }
    }
}

// XOR-mask of initial qubits whose cos(theta) multiply into final <Z_q>.
__constant__ unsigned short kSMask[12] = {
    0xAAB, 0xFFD, 0xFFA, 0xFF5, 0xFEA, 0xFD5,
    0xFAA, 0xF55, 0xEAA, 0xD55, 0xAAA, 0x555
};

// One block per batch row: z = h2 @ W3^T + b3; theta = z + qp; qz = masked cos-products.
__global__ __launch_bounds__(256) void enc3_quantum(
    const float* __restrict__ H2,  // 2048 x 1024
    const float* __restrict__ W3,  // 12 x 1024
    const float* __restrict__ b3,  // 12
    const float* __restrict__ qp,  // 12
    float* __restrict__ QZ)        // 2048 x 12
{
    const int b    = blockIdx.x;
    const int t    = threadIdx.x;      // 0..255
    const int lane = t & 63;
    const int wid  = t >> 6;           // 0..3

    float h[4];
    #pragma unroll
    for (int i = 0; i < 4; ++i) h[i] = H2[(size_t)b * 1024 + t + i * 256];

    __shared__ float wred[4][12];
    __shared__ float ctheta[12];

    #pragma unroll 1
    for (int n = 0; n < 12; ++n) {
        float p = 0.f;
        #pragma unroll
        for (int i = 0; i < 4; ++i)
            p = fmaf(h[i], W3[n * 1024 + t + i * 256], p);
        #pragma unroll
        for (int off = 32; off > 0; off >>= 1)
            p += __shfl_down(p, off);
        if (lane == 0) wred[wid][n] = p;
    }
    __syncthreads();

    if (t < 12) {
        float z = wred[0][t] + wred[1][t] + wred[2][t] + wred[3][t]
                + b3[t] + qp[t];
        ctheta[t] = cosf(z);
    }
    __syncthreads();

    if (t < 12) {
        const unsigned m = kSMask[t];
        float prod = 1.f;
        #pragma unroll
        for (int j = 0; j < 12; ++j)
            if ((m >> j) & 1) prod *= ctheta[j];
        QZ[(size_t)b * 12 + t] = prod;
    }
}

extern "C" void kernel_launch(void* const* d_in, const int* in_sizes, int n_in,
                              void* d_out, int out_size, void* d_ws, size_t ws_size,
                              hipStream_t stream) {
    const float* x   = (const float*)d_in[0];
    const float* w1  = (const float*)d_in[1];
    const float* b1  = (const float*)d_in[2];
    const float* w2  = (const float*)d_in[3];
    const float* b2  = (const float*)d_in[4];
    const float* w3  = (const float*)d_in[5];
    const float* b3  = (const float*)d_in[6];
    const float* qp  = (const float*)d_in[7];
    const float* dw1 = (const float*)d_in[8];
    const float* db1 = (const float*)d_in[9];
    const float* dw2 = (const float*)d_in[10];
    const float* db2 = (const float*)d_in[11];
    const float* dw3 = (const float*)d_in[12];
    const float* db3 = (const float*)d_in[13];
    float* out = (float*)d_out;

    const int B = 2048, D = 4096, H1 = 2048, H2 = 1024;

    float* h1 = (float*)d_ws;                 // B*H1
    float* h2 = h1 + (size_t)B * H1;          // B*H2
    float* qz = h2 + (size_t)B * H2;          // B*12
    float* h3 = qz + (size_t)B * 12;          // B*H2
    float* h4 = h3 + (size_t)B * H2;          // B*H1
    // total: 2*B*H1 + 2*B*H2 + B*12 floats ~= 50.4 MB — well within d_ws.

    dim3 blk(256);

    gemm_bias_act<true ><<<dim3(H1 / TN, B / TM), blk, 0, stream>>>(x,  w1,  b1,  h1,  B, H1, D);
    gemm_bias_act<true ><<<dim3(H2 / TN, B / TM), blk, 0, stream>>>(h1, w2,  b2,  h2,  B, H2, H1);
    enc3_quantum<<<dim3(B), blk, 0, stream>>>(h2, w3, b3, qp, qz);
    gemm_bias_act<true ><<<dim3(H2 / TN, B / TM), blk, 0, stream>>>(qz, dw1, db1, h3,  B, H2, 12);
    gemm_bias_act<true ><<<dim3(H1 / TN, B / TM), blk, 0, stream>>>(h3, dw2, db2, h4,  B, H1, H2);
    gemm_bias_act<false><<<dim3(D  / TN, B / TM), blk, 0, stream>>>(h4, dw3, db3, out, B, D,  H1);
}

// Round 2
// 271.024 us; speedup vs baseline: 5.0364x; 5.0364x over previous
//
#include <hip/hip_runtime.h>
#include <hip/hip_bf16.h>

// ---------------------------------------------------------------------------
// HybridAutoEncoder on MI355X — bf16 MFMA version.
//
//   h1 = relu(x @ W1^T + b1)          bf16 MFMA GEMM 2048x2048x4096 -> bf16
//   h2 = relu(h1 @ W2^T + b2)         bf16 MFMA GEMM 2048x1024x2048 -> f32
//   z  = h2 @ W3^T + b3  (fp32)       fused into quantum kernel
//   qz[b,q] = prod_{j in S_q} cos(z[b,j]+qp[j])   (analytic quantum latent)
//   h3 = relu(qz @ dW1^T + db1)       fp32 K=12 kernel -> bf16
//   h4 = relu(h3 @ dW2^T + db2)       bf16 MFMA GEMM 2048x2048x1024 -> bf16
//   out= h4 @ dW3^T + db3             bf16 MFMA GEMM 2048x4096x2048 -> f32
//
// GEMM kernel = m97 structure: 128x128 tile, 4 waves (2x2 of 64x64),
// mfma_f32_16x16x32_bf16, global_load_lds(16B) staging, linear LDS [128][32],
// NT layout (weights are [N][K] so B-fragments are contiguous 16B).
// ---------------------------------------------------------------------------

typedef __bf16 bf16x8 __attribute__((ext_vector_type(8)));
typedef __bf16 bf16x4 __attribute__((ext_vector_type(4)));
typedef float  f32x4  __attribute__((ext_vector_type(4)));

__device__ __forceinline__ void async16(const void* g, void* l) {
    __builtin_amdgcn_global_load_lds(
        (const __attribute__((address_space(1))) unsigned int*)g,
        (__attribute__((address_space(3))) unsigned int*)l,
        16, 0, 0);
}

// C = act(A @ W^T + bias). A: M x K bf16 row-major. W: N x K bf16 row-major.
template <typename TOUT, bool RELU>
__global__ __launch_bounds__(256) void gemm_bf16_mfma(
    const __bf16* __restrict__ A, const __bf16* __restrict__ W,
    const float* __restrict__ bias, TOUT* __restrict__ C,
    int M, int N, int K)
{
    __shared__ uint4 smem4[1024];           // 16 KB: A-tile @0 (8KB), B-tile @8192
    char* smem = (char*)smem4;

    const int t    = threadIdx.x;
    const int lane = t & 63;
    const int wid  = t >> 6;                 // 0..3
    const int bm   = blockIdx.y * 128;
    const int bn   = blockIdx.x * 128;

    // staging decomposition: lane -> (row within 16-row wave chunk, k-offset)
    const int r4 = lane >> 2;                // 0..15
    const int c8 = (lane & 3) * 8;           // k elem offset 0,8,16,24
    // fragment decomposition
    const int lm = lane & 15;
    const int lh = lane >> 4;                // 0..3
    const int wm = wid >> 1;                 // wave row (0..1)
    const int wn = wid & 1;                  // wave col (0..1)

    f32x4 acc[4][4] = {};

    const __bf16* gA0 = A + (size_t)(bm + wid * 16 + r4) * K + c8;
    const __bf16* gA1 = gA0 + (size_t)64 * K;
    const __bf16* gB0 = W + (size_t)(bn + wid * 16 + r4) * K + c8;
    const __bf16* gB1 = gB0 + (size_t)64 * K;
    char* lA = smem + wid * 1024;            // + j*4096 per 64-row half
    char* lB = smem + 8192 + wid * 1024;

    for (int k0 = 0; k0 < K; k0 += 32) {
        async16(gA0 + k0, lA);
        async16(gA1 + k0, lA + 4096);
        async16(gB0 + k0, lB);
        async16(gB1 + k0, lB + 4096);
        __syncthreads();                      // drains vmcnt before barrier

        bf16x8 a[4], b[4];
        #pragma unroll
        for (int i = 0; i < 4; ++i) {
            a[i] = *(const bf16x8*)(smem + (wm * 64 + i * 16 + lm) * 64 + lh * 16);
            b[i] = *(const bf16x8*)(smem + 8192 + (wn * 64 + i * 16 + lm) * 64 + lh * 16);
        }
        #pragma unroll
        for (int i = 0; i < 4; ++i)
            #pragma unroll
            for (int j = 0; j < 4; ++j)
                acc[i][j] = __builtin_amdgcn_mfma_f32_16x16x32_bf16(
                    a[i], b[j], acc[i][j], 0, 0, 0);
        __syncthreads();
    }

    #pragma unroll
    for (int i = 0; i < 4; ++i) {
        const int row0 = bm + wm * 64 + i * 16 + lh * 4;
        #pragma unroll
        for (int j = 0; j < 4; ++j) {
            const int col = bn + wn * 64 + j * 16 + lm;
            const float bv = bias[col];
            #pragma unroll
            for (int r = 0; r < 4; ++r) {
                float v = acc[i][j][r] + bv;
                if (RELU) v = fmaxf(v, 0.f);
                C[(size_t)(row0 + r) * N + col] = (TOUT)v;
            }
        }
    }
}

// fp32 -> bf16 cast, 8 elems/thread.
__global__ __launch_bounds__(256) void cvt_bf16(
    const float* __restrict__ in, __bf16* __restrict__ out, int n8)
{
    int i = blockIdx.x * blockDim.x + threadIdx.x;
    if (i >= n8) return;
    const float4* p = reinterpret_cast<const float4*>(in) + (size_t)i * 2;
    float4 a = p[0], b = p[1];
    bf16x8 v;
    v[0] = (__bf16)a.x; v[1] = (__bf16)a.y; v[2] = (__bf16)a.z; v[3] = (__bf16)a.w;
    v[4] = (__bf16)b.x; v[5] = (__bf16)b.y; v[6] = (__bf16)b.z; v[7] = (__bf16)b.w;
    reinterpret_cast<bf16x8*>(out)[i] = v;
}

// XOR-mask of initial qubits whose cos(theta) multiply into final <Z_q>.
__constant__ unsigned short kSMask[12] = {
    0xAAB, 0xFFD, 0xFFA, 0xFF5, 0xFEA, 0xFD5,
    0xFAA, 0xF55, 0xEAA, 0xD55, 0xAAA, 0x555
};

// One block per batch row: z = h2 @ W3^T + b3; theta = z + qp; qz = masked cos-products.
__global__ __launch_bounds__(256) void enc3_quantum(
    const float* __restrict__ H2,  // 2048 x 1024 (f32)
    const float* __restrict__ W3,  // 12 x 1024
    const float* __restrict__ b3,  // 12
    const float* __restrict__ qp,  // 12
    float* __restrict__ QZ)        // 2048 x 12
{
    const int b    = blockIdx.x;
    const int t    = threadIdx.x;
    const int lane = t & 63;
    const int wid  = t >> 6;

    float h[4];
    #pragma unroll
    for (int i = 0; i < 4; ++i) h[i] = H2[(size_t)b * 1024 + t + i * 256];

    __shared__ float wred[4][12];
    __shared__ float ctheta[12];

    #pragma unroll 1
    for (int n = 0; n < 12; ++n) {
        float p = 0.f;
        #pragma unroll
        for (int i = 0; i < 4; ++i)
            p = fmaf(h[i], W3[n * 1024 + t + i * 256], p);
        #pragma unroll
        for (int off = 32; off > 0; off >>= 1)
            p += __shfl_down(p, off);
        if (lane == 0) wred[wid][n] = p;
    }
    __syncthreads();

    if (t < 12) {
        float z = wred[0][t] + wred[1][t] + wred[2][t] + wred[3][t]
                + b3[t] + qp[t];
        ctheta[t] = cosf(z);
    }
    __syncthreads();

    if (t < 12) {
        const unsigned m = kSMask[t];
        float prod = 1.f;
        #pragma unroll
        for (int j = 0; j < 12; ++j)
            if ((m >> j) & 1) prod *= ctheta[j];
        QZ[(size_t)b * 12 + t] = prod;
    }
}

// h3 = relu(qz @ dW1^T + db1) -> bf16. One block per batch row, 4 outputs/thread.
__global__ __launch_bounds__(256) void dec1_small(
    const float* __restrict__ QZ,   // 2048 x 12
    const float* __restrict__ dW1,  // 1024 x 12
    const float* __restrict__ db1,  // 1024
    __bf16* __restrict__ H3)        // 2048 x 1024 (bf16)
{
    const int b = blockIdx.x;
    const int t = threadIdx.x;
    __shared__ float q[12];
    if (t < 12) q[t] = QZ[(size_t)b * 12 + t];
    __syncthreads();

    bf16x4 v;
    #pragma unroll
    for (int j = 0; j < 4; ++j) {
        const int n = t * 4 + j;
        float acc = db1[n];
        #pragma unroll
        for (int k = 0; k < 12; ++k)
            acc = fmaf(q[k], dW1[n * 12 + k], acc);
        v[j] = (__bf16)fmaxf(acc, 0.f);
    }
    *reinterpret_cast<bf16x4*>(&H3[(size_t)b * 1024 + t * 4]) = v;
}

extern "C" void kernel_launch(void* const* d_in, const int* in_sizes, int n_in,
                              void* d_out, int out_size, void* d_ws, size_t ws_size,
                              hipStream_t stream) {
    const float* x   = (const float*)d_in[0];
    const float* w1  = (const float*)d_in[1];
    const float* b1  = (const float*)d_in[2];
    const float* w2  = (const float*)d_in[3];
    const float* b2  = (const float*)d_in[4];
    const float* w3  = (const float*)d_in[5];
    const float* b3  = (const float*)d_in[6];
    const float* qp  = (const float*)d_in[7];
    const float* dw1 = (const float*)d_in[8];
    const float* db1 = (const float*)d_in[9];
    const float* dw2 = (const float*)d_in[10];
    const float* db2 = (const float*)d_in[11];
    const float* dw3 = (const float*)d_in[12];
    const float* db3 = (const float*)d_in[13];
    float* out = (float*)d_out;

    const int B = 2048, D = 4096, H1 = 2048, H2 = 1024;

    // Workspace slots (bytes), reused across stages. Peak ~42.1 MB.
    char* ws = (char*)d_ws;
    __bf16* SA   = (__bf16*)(ws);                    // 16.78 MB: w1bf -> w2bf -> dw2bf -> dw3bf
    char*   SBc  = ws + 16777216;                    // 16.78 MB: xbf -> h2(f32) -> h4bf
    __bf16* SB_bf = (__bf16*)SBc;
    float*  SB_f  = (float*)SBc;
    __bf16* SC   = (__bf16*)(ws + 33554432);         //  8.39 MB: h1bf -> h3bf
    float*  QZ   = (float*)(ws + 41943040);          //  0.10 MB

    dim3 blk(256);

    // enc1: h1 = relu(x @ w1^T + b1)
    cvt_bf16<<<dim3((B * D / 8 + 255) / 256), blk, 0, stream>>>(x,  SB_bf, B * D / 8);
    cvt_bf16<<<dim3((H1 * D / 8 + 255) / 256), blk, 0, stream>>>(w1, SA,    H1 * D / 8);
    gemm_bf16_mfma<__bf16, true><<<dim3(H1 / 128, B / 128), blk, 0, stream>>>(
        SB_bf, SA, b1, SC, B, H1, D);

    // enc2: h2 = relu(h1 @ w2^T + b2)  (f32 out for the z-path)
    cvt_bf16<<<dim3((H2 * H1 / 8 + 255) / 256), blk, 0, stream>>>(w2, SA, H2 * H1 / 8);
    gemm_bf16_mfma<float, true><<<dim3(H2 / 128, B / 128), blk, 0, stream>>>(
        SC, SA, b2, SB_f, B, H2, H1);

    // enc3 + quantum latent
    enc3_quantum<<<dim3(B), blk, 0, stream>>>(SB_f, w3, b3, qp, QZ);

    // dec1 (K=12): h3 = relu(qz @ dw1^T + db1) -> bf16
    dec1_small<<<dim3(B), blk, 0, stream>>>(QZ, dw1, db1, SC);

    // dec2: h4 = relu(h3 @ dw2^T + db2)
    cvt_bf16<<<dim3((H1 * H2 / 8 + 255) / 256), blk, 0, stream>>>(dw2, SA, H1 * H2 / 8);
    gemm_bf16_mfma<__bf16, true><<<dim3(H1 / 128, B / 128), blk, 0, stream>>>(
        SC, SA, db2, SB_bf, B, H1, H2);

    // dec3: out = h4 @ dw3^T + db3 -> f32
    cvt_bf16<<<dim3((D * H1 / 8 + 255) / 256), blk, 0, stream>>>(dw3, SA, D * H1 / 8);
    gemm_bf16_mfma<float, false><<<dim3(D / 128, B / 128), blk, 0, stream>>>(
        SB_bf, SA, db3, out, B, D, H1);
}

// Round 3
// 185.595 us; speedup vs baseline: 7.3547x; 1.4603x over previous
//
#include <hip/hip_runtime.h>
#include <hip/hip_bf16.h>

// ---------------------------------------------------------------------------
// HybridAutoEncoder on MI355X — bf16 MFMA, pipelined ring-buffer GEMM.
//
// GEMM: 128x128 tile, BK=64, 4 waves (2x2 of 64x64), 3-buffer LDS ring,
// prefetch depth 2, counted s_waitcnt vmcnt(8), one s_barrier per K-tile,
// XOR-swizzled LDS (pre-swizzled global source + swizzled ds_read, rule 21),
// s_setprio(1) around the MFMA cluster.
// ---------------------------------------------------------------------------

typedef __bf16 bf16x8 __attribute__((ext_vector_type(8)));
typedef __bf16 bf16x4 __attribute__((ext_vector_type(4)));
typedef float  f32x4  __attribute__((ext_vector_type(4)));

__device__ __forceinline__ void async16(const void* g, void* l) {
    __builtin_amdgcn_global_load_lds(
        (const __attribute__((address_space(1))) unsigned int*)g,
        (__attribute__((address_space(3))) unsigned int*)l,
        16, 0, 0);
}

// C = act(A @ W^T + bias). A: M x K bf16 row-major. W: N x K bf16 row-major.
// K must be a multiple of 64 with K/64 >= 3; M,N multiples of 128.
template <typename TOUT, bool RELU>
__global__ __launch_bounds__(256) void gemm_bf16_pipe(
    const __bf16* __restrict__ A, const __bf16* __restrict__ W,
    const float* __restrict__ bias, TOUT* __restrict__ C,
    int M, int N, int K)
{
    extern __shared__ char smem[];           // 3 bufs x 32KB (A 16KB + B 16KB)

    const int t    = threadIdx.x;
    const int lane = t & 63;
    const int w    = t >> 6;                 // wave 0..3
    const int bm   = blockIdx.y * 128;
    const int bn   = blockIdx.x * 128;

    // ---- staging decomposition (8 lanes per row, swizzled source col) ----
    const int sr  = lane >> 3;               // row within 8-row chunk (== row&7)
    const int scs = (lane & 7) ^ sr;         // swizzled source col-slot (8 bf16)
    const __bf16* gA = A + (size_t)(bm + w * 8 + sr) * K + scs * 8;
    const __bf16* gB = W + (size_t)(bn + w * 8 + sr) * K + scs * 8;
    const size_t rowj = (size_t)32 * K;      // +32 rows per load j

    // ---- fragment decomposition ----
    const int lm = lane & 15;
    const int lh = lane >> 4;                // 0..3
    const int wm = w >> 1, wn = w & 1;
    const int axor = lm & 7;                 // row&7 for all fragment rows

    f32x4 acc[4][4] = {};

    #define STAGE(BUF, TT)                                              \
        {                                                               \
            char* la = smem + (BUF) * 32768 + w * 1024;                 \
            char* lb = la + 16384;                                      \
            const __bf16* ga = gA + (size_t)(TT) * 64;                  \
            const __bf16* gb = gB + (size_t)(TT) * 64;                  \
            _Pragma("unroll")                                           \
            for (int j = 0; j < 4; ++j) {                               \
                async16(ga + rowj * j, la + j * 4096);                  \
                async16(gb + rowj * j, lb + j * 4096);                  \
            }                                                           \
        }

    #define COMPUTE(BUF)                                                \
        {                                                               \
            char* base = smem + (BUF) * 32768;                          \
            bf16x8 a[2][4], b[2][4];                                    \
            _Pragma("unroll")                                           \
            for (int kh = 0; kh < 2; ++kh) {                            \
                _Pragma("unroll")                                       \
                for (int i = 0; i < 4; ++i) {                           \
                    const int sl = ((kh * 4 + lh) ^ axor) * 16;         \
                    a[kh][i] = *(const bf16x8*)(base +                  \
                        (wm * 64 + i * 16 + lm) * 128 + sl);            \
                    b[kh][i] = *(const bf16x8*)(base + 16384 +          \
                        (wn * 64 + i * 16 + lm) * 128 + sl);            \
                }                                                       \
            }                                                           \
            __builtin_amdgcn_s_setprio(1);                              \
            _Pragma("unroll")                                           \
            for (int kh = 0; kh < 2; ++kh)                              \
                _Pragma("unroll")                                       \
                for (int i = 0; i < 4; ++i)                             \
                    _Pragma("unroll")                                   \
                    for (int j = 0; j < 4; ++j)                         \
                        acc[i][j] = __builtin_amdgcn_mfma_f32_16x16x32_bf16( \
                            a[kh][i], b[kh][j], acc[i][j], 0, 0, 0);    \
            __builtin_amdgcn_s_setprio(0);                              \
        }

    #define WAITBAR(VM)                                                 \
        asm volatile("s_waitcnt vmcnt(" #VM ") lgkmcnt(0)" ::: "memory"); \
        __builtin_amdgcn_s_barrier();                                   \
        __builtin_amdgcn_sched_barrier(0);

    const int NT = K >> 6;
    STAGE(0, 0);
    STAGE(1, 1);

    int cbuf = 0, sbuf = 2;
    for (int tt = 0; tt < NT - 2; ++tt) {
        WAITBAR(8);                  // tile tt landed; tile tt+1 still in flight
        STAGE(sbuf, tt + 2);
        COMPUTE(cbuf);
        cbuf = (cbuf == 2) ? 0 : cbuf + 1;
        sbuf = (sbuf == 2) ? 0 : sbuf + 1;
    }
    WAITBAR(8);
    COMPUTE(cbuf);
    cbuf = (cbuf == 2) ? 0 : cbuf + 1;
    WAITBAR(0);
    COMPUTE(cbuf);

    #undef STAGE
    #undef COMPUTE
    #undef WAITBAR

    // ---- epilogue ----
    #pragma unroll
    for (int i = 0; i < 4; ++i) {
        const int row0 = bm + wm * 64 + i * 16 + lh * 4;
        #pragma unroll
        for (int j = 0; j < 4; ++j) {
            const int col = bn + wn * 64 + j * 16 + lm;
            const float bv = bias[col];
            #pragma unroll
            for (int r = 0; r < 4; ++r) {
                float v = acc[i][j][r] + bv;
                if (RELU) v = fmaxf(v, 0.f);
                C[(size_t)(row0 + r) * N + col] = (TOUT)v;
            }
        }
    }
}

// fp32 -> bf16 cast, 8 elems/thread.
__global__ __launch_bounds__(256) void cvt_bf16(
    const float* __restrict__ in, __bf16* __restrict__ out, int n8)
{
    int i = blockIdx.x * blockDim.x + threadIdx.x;
    if (i >= n8) return;
    const float4* p = reinterpret_cast<const float4*>(in) + (size_t)i * 2;
    float4 a = p[0], b = p[1];
    bf16x8 v;
    v[0] = (__bf16)a.x; v[1] = (__bf16)a.y; v[2] = (__bf16)a.z; v[3] = (__bf16)a.w;
    v[4] = (__bf16)b.x; v[5] = (__bf16)b.y; v[6] = (__bf16)b.z; v[7] = (__bf16)b.w;
    reinterpret_cast<bf16x8*>(out)[i] = v;
}

// XOR-mask of initial qubits whose cos(theta) multiply into final <Z_q>.
__constant__ unsigned short kSMask[12] = {
    0xAAB, 0xFFD, 0xFFA, 0xFF5, 0xFEA, 0xFD5,
    0xFAA, 0xF55, 0xEAA, 0xD55, 0xAAA, 0x555
};

// One block per batch row: z = h2 @ W3^T + b3; theta = z + qp; qz = masked cos-products.
__global__ __launch_bounds__(256) void enc3_quantum(
    const float* __restrict__ H2,  // 2048 x 1024 (f32)
    const float* __restrict__ W3,  // 12 x 1024
    const float* __restrict__ b3,  // 12
    const float* __restrict__ qp,  // 12
    float* __restrict__ QZ)        // 2048 x 12
{
    const int b    = blockIdx.x;
    const int t    = threadIdx.x;
    const int lane = t & 63;
    const int wid  = t >> 6;

    float h[4];
    #pragma unroll
    for (int i = 0; i < 4; ++i) h[i] = H2[(size_t)b * 1024 + t + i * 256];

    __shared__ float wred[4][12];
    __shared__ float ctheta[12];

    #pragma unroll 1
    for (int n = 0; n < 12; ++n) {
        float p = 0.f;
        #pragma unroll
        for (int i = 0; i < 4; ++i)
            p = fmaf(h[i], W3[n * 1024 + t + i * 256], p);
        #pragma unroll
        for (int off = 32; off > 0; off >>= 1)
            p += __shfl_down(p, off);
        if (lane == 0) wred[wid][n] = p;
    }
    __syncthreads();

    if (t < 12) {
        float z = wred[0][t] + wred[1][t] + wred[2][t] + wred[3][t]
                + b3[t] + qp[t];
        ctheta[t] = cosf(z);
    }
    __syncthreads();

    if (t < 12) {
        const unsigned m = kSMask[t];
        float prod = 1.f;
        #pragma unroll
        for (int j = 0; j < 12; ++j)
            if ((m >> j) & 1) prod *= ctheta[j];
        QZ[(size_t)b * 12 + t] = prod;
    }
}

// h3 = relu(qz @ dW1^T + db1) -> bf16. One block per batch row, 4 outputs/thread.
__global__ __launch_bounds__(256) void dec1_small(
    const float* __restrict__ QZ,   // 2048 x 12
    const float* __restrict__ dW1,  // 1024 x 12
    const float* __restrict__ db1,  // 1024
    __bf16* __restrict__ H3)        // 2048 x 1024 (bf16)
{
    const int b = blockIdx.x;
    const int t = threadIdx.x;
    __shared__ float q[12];
    if (t < 12) q[t] = QZ[(size_t)b * 12 + t];
    __syncthreads();

    bf16x4 v;
    #pragma unroll
    for (int j = 0; j < 4; ++j) {
        const int n = t * 4 + j;
        float acc = db1[n];
        #pragma unroll
        for (int k = 0; k < 12; ++k)
            acc = fmaf(q[k], dW1[n * 12 + k], acc);
        v[j] = (__bf16)fmaxf(acc, 0.f);
    }
    *reinterpret_cast<bf16x4*>(&H3[(size_t)b * 1024 + t * 4]) = v;
}

extern "C" void kernel_launch(void* const* d_in, const int* in_sizes, int n_in,
                              void* d_out, int out_size, void* d_ws, size_t ws_size,
                              hipStream_t stream) {
    const float* x   = (const float*)d_in[0];
    const float* w1  = (const float*)d_in[1];
    const float* b1  = (const float*)d_in[2];
    const float* w2  = (const float*)d_in[3];
    const float* b2  = (const float*)d_in[4];
    const float* w3  = (const float*)d_in[5];
    const float* b3  = (const float*)d_in[6];
    const float* qp  = (const float*)d_in[7];
    const float* dw1 = (const float*)d_in[8];
    const float* db1 = (const float*)d_in[9];
    const float* dw2 = (const float*)d_in[10];
    const float* db2 = (const float*)d_in[11];
    const float* dw3 = (const float*)d_in[12];
    const float* db3 = (const float*)d_in[13];
    float* out = (float*)d_out;

    const int B = 2048, D = 4096, H1 = 2048, H2 = 1024;
    const int SMEM = 98304;

    static int attr_done = 0;
    if (!attr_done) {
        hipFuncSetAttribute((const void*)&gemm_bf16_pipe<__bf16, true>,
                            hipFuncAttributeMaxDynamicSharedMemorySize, SMEM);
        hipFuncSetAttribute((const void*)&gemm_bf16_pipe<float, true>,
                            hipFuncAttributeMaxDynamicSharedMemorySize, SMEM);
        hipFuncSetAttribute((const void*)&gemm_bf16_pipe<float, false>,
                            hipFuncAttributeMaxDynamicSharedMemorySize, SMEM);
        attr_done = 1;
    }

    // Workspace slots (bytes), reused across stages. Peak ~42.1 MB.
    char* ws = (char*)d_ws;
    __bf16* SA    = (__bf16*)(ws);                   // w1bf -> w2bf -> dw2bf -> dw3bf
    char*   SBc   = ws + 16777216;                   // xbf -> h2(f32) -> h4bf
    __bf16* SB_bf = (__bf16*)SBc;
    float*  SB_f  = (float*)SBc;
    __bf16* SC    = (__bf16*)(ws + 33554432);        // h1bf -> h3bf
    float*  QZ    = (float*)(ws + 41943040);

    dim3 blk(256);

    // enc1: h1 = relu(x @ w1^T + b1)
    cvt_bf16<<<dim3(B * D / 8 / 256), blk, 0, stream>>>(x,  SB_bf, B * D / 8);
    cvt_bf16<<<dim3(H1 * D / 8 / 256), blk, 0, stream>>>(w1, SA,    H1 * D / 8);
    gemm_bf16_pipe<__bf16, true><<<dim3(H1 / 128, B / 128), blk, SMEM, stream>>>(
        SB_bf, SA, b1, SC, B, H1, D);

    // enc2: h2 = relu(h1 @ w2^T + b2)  (f32 out for the z-path)
    cvt_bf16<<<dim3(H2 * H1 / 8 / 256), blk, 0, stream>>>(w2, SA, H2 * H1 / 8);
    gemm_bf16_pipe<float, true><<<dim3(H2 / 128, B / 128), blk, SMEM, stream>>>(
        SC, SA, b2, SB_f, B, H2, H1);

    // enc3 + quantum latent
    enc3_quantum<<<dim3(B), blk, 0, stream>>>(SB_f, w3, b3, qp, QZ);

    // dec1 (K=12): h3 = relu(qz @ dw1^T + db1) -> bf16
    dec1_small<<<dim3(B), blk, 0, stream>>>(QZ, dw1, db1, SC);

    // dec2: h4 = relu(h3 @ dw2^T + db2)
    cvt_bf16<<<dim3(H1 * H2 / 8 / 256), blk, 0, stream>>>(dw2, SA, H1 * H2 / 8);
    gemm_bf16_pipe<__bf16, true><<<dim3(H1 / 128, B / 128), blk, SMEM, stream>>>(
        SC, SA, db2, SB_bf, B, H1, H2);

    // dec3: out = h4 @ dw3^T + db3 -> f32
    cvt_bf16<<<dim3(D * H1 / 8 / 256), blk, 0, stream>>>(dw3, SA, D * H1 / 8);
    gemm_bf16_pipe<float, false><<<dim3(D / 128, B / 128), blk, SMEM, stream>>>(
        SB_bf, SA, db3, out, B, D, H1);
}

// Round 4
// 153.771 us; speedup vs baseline: 8.8768x; 1.2070x over previous
//
#include <hip/hip_runtime.h>
#include <hip/hip_bf16.h>

// ---------------------------------------------------------------------------
// HybridAutoEncoder on MI355X — bf16 MFMA, double-buffered pipelined GEMM,
// tile sizes chosen per-layer so every grid >= 512 wgs (2 blocks/CU).
//
//   enc1: relu(x@W1^T+b1)    gemm<128,64>  grid 512   K=4096
//   enc2: relu(h1@W2^T+b2)   gemm<64,64>   grid 512   K=2048  (f32 out)
//   enc3+quantum+dec1 fused  (analytic quantum latent, masked cos-products)
//   dec2: relu(h3@dW2^T+db2) gemm<128,64>  grid 512   K=1024
//   dec3: h4@dW3^T+db3       gemm<128,128> grid 512   K=2048  (f32 out)
//
// GEMM: BK=64, 4 waves (2x2), XOR-swizzled LDS (pre-swizzled global source +
// swizzled ds_read), double-buffer, counted s_waitcnt vmcnt(L), setprio(1)
// around the MFMA cluster.
// ---------------------------------------------------------------------------

typedef __bf16 bf16x8 __attribute__((ext_vector_type(8)));
typedef __bf16 bf16x4 __attribute__((ext_vector_type(4)));
typedef float  f32x4  __attribute__((ext_vector_type(4)));

__device__ __forceinline__ void async16(const void* g, void* l) {
    __builtin_amdgcn_global_load_lds(
        (const __attribute__((address_space(1))) unsigned int*)g,
        (__attribute__((address_space(3))) unsigned int*)l,
        16, 0, 0);
}

template<int VM> __device__ __forceinline__ void wait_vm_lgkm0() {
    if constexpr (VM == 0)      asm volatile("s_waitcnt vmcnt(0) lgkmcnt(0)" ::: "memory");
    else if constexpr (VM == 4) asm volatile("s_waitcnt vmcnt(4) lgkmcnt(0)" ::: "memory");
    else if constexpr (VM == 6) asm volatile("s_waitcnt vmcnt(6) lgkmcnt(0)" ::: "memory");
    else if constexpr (VM == 8) asm volatile("s_waitcnt vmcnt(8) lgkmcnt(0)" ::: "memory");
    else static_assert(VM == 0 || VM == 4 || VM == 6 || VM == 8, "unsupported VM");
}

// C = act(A @ W^T + bias). A: M x K bf16 row-major. W: N x K bf16 row-major.
// K multiple of 64, NT >= 2. Grid (N/BN, M/BM). Dynamic LDS = 2*(BM+BN)*128 B.
template <int BM, int BN, typename TOUT, bool RELU>
__global__ __launch_bounds__(256) void gemm_pipe(
    const __bf16* __restrict__ A, const __bf16* __restrict__ W,
    const float* __restrict__ bias, TOUT* __restrict__ C,
    int M, int N, int K)
{
    constexpr int CHA = BM / 32, CHB = BN / 32, LLOADS = CHA + CHB;
    constexpr int ABYTES = BM * 128, BUFB = (BM + BN) * 128;
    constexpr int WMR = BM / 2, WNC = BN / 2;      // wave tile (2x2 waves)
    constexpr int NI = WMR / 16, NJ = WNC / 16;

    extern __shared__ char smem[];

    const int t    = threadIdx.x;
    const int lane = t & 63;
    const int w    = t >> 6;
    const int bm   = blockIdx.y * BM;
    const int bn   = blockIdx.x * BN;

    // staging: 8 lanes per row, XOR-swizzled source col-slot (rule 21)
    const int sr  = lane >> 3;
    const int scs = (lane & 7) ^ sr;
    const __bf16* gA = A + (size_t)(bm + w * 8 + sr) * K + scs * 8;
    const __bf16* gB = W + (size_t)(bn + w * 8 + sr) * K + scs * 8;

    // fragments
    const int lm = lane & 15;
    const int lh = lane >> 4;
    const int wm = w >> 1, wn = w & 1;
    const int axor = lm & 7;

    f32x4 acc[NI][NJ] = {};

    auto STAGE = [&](int buf, int tt) {
        char* la = smem + buf * BUFB + w * 1024;
        char* lb = smem + buf * BUFB + ABYTES + w * 1024;
        const __bf16* ga = gA + (size_t)tt * 64;
        const __bf16* gb = gB + (size_t)tt * 64;
        #pragma unroll
        for (int j = 0; j < CHA; ++j) async16(ga + (size_t)32 * K * j, la + j * 4096);
        #pragma unroll
        for (int j = 0; j < CHB; ++j) async16(gb + (size_t)32 * K * j, lb + j * 4096);
    };

    auto COMPUTE = [&](int buf) {
        char* base = smem + buf * BUFB;
        bf16x8 a[2][NI], b[2][NJ];
        #pragma unroll
        for (int kh = 0; kh < 2; ++kh) {
            #pragma unroll
            for (int i = 0; i < NI; ++i)
                a[kh][i] = *(const bf16x8*)(base + (wm * WMR + i * 16 + lm) * 128
                                            + ((kh * 4 + lh) ^ axor) * 16);
            #pragma unroll
            for (int j = 0; j < NJ; ++j)
                b[kh][j] = *(const bf16x8*)(base + ABYTES + (wn * WNC + j * 16 + lm) * 128
                                            + ((kh * 4 + lh) ^ axor) * 16);
        }
        __builtin_amdgcn_s_setprio(1);
        #pragma unroll
        for (int kh = 0; kh < 2; ++kh)
            #pragma unroll
            for (int i = 0; i < NI; ++i)
                #pragma unroll
                for (int j = 0; j < NJ; ++j)
                    acc[i][j] = __builtin_amdgcn_mfma_f32_16x16x32_bf16(
                        a[kh][i], b[kh][j], acc[i][j], 0, 0, 0);
        __builtin_amdgcn_s_setprio(0);
    };

    const int NT = K >> 6;
    STAGE(0, 0);
    STAGE(1, 1);

    for (int tt = 0; tt < NT; ++tt) {
        if (tt < NT - 1) wait_vm_lgkm0<LLOADS>();
        else             wait_vm_lgkm0<0>();
        __builtin_amdgcn_s_barrier();
        __builtin_amdgcn_sched_barrier(0);
        COMPUTE(tt & 1);
        if (tt + 2 < NT) {
            asm volatile("s_waitcnt lgkmcnt(0)" ::: "memory");
            __builtin_amdgcn_s_barrier();
            __builtin_amdgcn_sched_barrier(0);
            STAGE(tt & 1, tt + 2);
        }
    }

    #pragma unroll
    for (int i = 0; i < NI; ++i) {
        const int row0 = bm + wm * WMR + i * 16 + lh * 4;
        #pragma unroll
        for (int j = 0; j < NJ; ++j) {
            const int col = bn + wn * WNC + j * 16 + lm;
            const float bv = bias[col];
            #pragma unroll
            for (int r = 0; r < 4; ++r) {
                float v = acc[i][j][r] + bv;
                if (RELU) v = fmaxf(v, 0.f);
                C[(size_t)(row0 + r) * N + col] = (TOUT)v;
            }
        }
    }
}

// ---- fused fp32->bf16 casts (8 elems / thread) ----
__device__ __forceinline__ void cvt8(const float* __restrict__ src,
                                     __bf16* __restrict__ dst, int g) {
    const float4* p = reinterpret_cast<const float4*>(src) + (size_t)g * 2;
    float4 a = p[0], b = p[1];
    bf16x8 v;
    v[0] = (__bf16)a.x; v[1] = (__bf16)a.y; v[2] = (__bf16)a.z; v[3] = (__bf16)a.w;
    v[4] = (__bf16)b.x; v[5] = (__bf16)b.y; v[6] = (__bf16)b.z; v[7] = (__bf16)b.w;
    reinterpret_cast<bf16x8*>(dst)[g] = v;
}

__global__ __launch_bounds__(256) void cvt_pair(
    const float* __restrict__ s0, __bf16* __restrict__ d0, int n0,
    const float* __restrict__ s1, __bf16* __restrict__ d1)
{
    int i = blockIdx.x * 256 + threadIdx.x;
    if (i < n0) cvt8(s0, d0, i);
    else        cvt8(s1, d1, i - n0);
}

__global__ __launch_bounds__(256) void cvt_triple(
    const float* __restrict__ s0, __bf16* __restrict__ d0, int n0,
    const float* __restrict__ s1, __bf16* __restrict__ d1, int n1,
    const float* __restrict__ s2, __bf16* __restrict__ d2)
{
    int i = blockIdx.x * 256 + threadIdx.x;
    if (i < n0)           cvt8(s0, d0, i);
    else if (i < n0 + n1) cvt8(s1, d1, i - n0);
    else                  cvt8(s2, d2, i - n0 - n1);
}

// XOR-mask of initial qubits whose cos(theta) multiply into final <Z_q>.
__constant__ unsigned short kSMask[12] = {
    0xAAB, 0xFFD, 0xFFA, 0xFF5, 0xFEA, 0xFD5,
    0xFAA, 0xF55, 0xEAA, 0xD55, 0xAAA, 0x555
};

// Fused: z = h2 @ W3^T + b3 ; qz = masked cos-products ; h3 = relu(qz@dW1^T+db1)
__global__ __launch_bounds__(256) void enc3q_dec1(
    const float* __restrict__ H2,   // 2048 x 1024 (f32)
    const float* __restrict__ W3,   // 12 x 1024
    const float* __restrict__ b3,   // 12
    const float* __restrict__ qp,   // 12
    const float* __restrict__ dW1,  // 1024 x 12
    const float* __restrict__ db1,  // 1024
    __bf16* __restrict__ H3)        // 2048 x 1024 (bf16)
{
    const int b    = blockIdx.x;
    const int t    = threadIdx.x;
    const int lane = t & 63;
    const int wid  = t >> 6;

    float h[4];
    #pragma unroll
    for (int i = 0; i < 4; ++i) h[i] = H2[(size_t)b * 1024 + t + i * 256];

    __shared__ float wred[4][12];
    __shared__ float ctheta[12];
    __shared__ float qz[12];

    #pragma unroll 1
    for (int n = 0; n < 12; ++n) {
        float p = 0.f;
        #pragma unroll
        for (int i = 0; i < 4; ++i)
            p = fmaf(h[i], W3[n * 1024 + t + i * 256], p);
        #pragma unroll
        for (int off = 32; off > 0; off >>= 1)
            p += __shfl_down(p, off);
        if (lane == 0) wred[wid][n] = p;
    }
    __syncthreads();

    if (t < 12) {
        float z = wred[0][t] + wred[1][t] + wred[2][t] + wred[3][t]
                + b3[t] + qp[t];
        ctheta[t] = cosf(z);
    }
    __syncthreads();

    if (t < 12) {
        const unsigned m = kSMask[t];
        float prod = 1.f;
        #pragma unroll
        for (int j = 0; j < 12; ++j)
            if ((m >> j) & 1) prod *= ctheta[j];
        qz[t] = prod;
    }
    __syncthreads();

    bf16x4 v;
    #pragma unroll
    for (int j = 0; j < 4; ++j) {
        const int n = t * 4 + j;
        float acc = db1[n];
        #pragma unroll
        for (int k = 0; k < 12; ++k)
            acc = fmaf(qz[k], dW1[n * 12 + k], acc);
        v[j] = (__bf16)fmaxf(acc, 0.f);
    }
    *reinterpret_cast<bf16x4*>(&H3[(size_t)b * 1024 + t * 4]) = v;
}

extern "C" void kernel_launch(void* const* d_in, const int* in_sizes, int n_in,
                              void* d_out, int out_size, void* d_ws, size_t ws_size,
                              hipStream_t stream) {
    const float* x   = (const float*)d_in[0];
    const float* w1  = (const float*)d_in[1];
    const float* b1  = (const float*)d_in[2];
    const float* w2  = (const float*)d_in[3];
    const float* b2  = (const float*)d_in[4];
    const float* w3  = (const float*)d_in[5];
    const float* b3  = (const float*)d_in[6];
    const float* qp  = (const float*)d_in[7];
    const float* dw1 = (const float*)d_in[8];
    const float* db1 = (const float*)d_in[9];
    const float* dw2 = (const float*)d_in[10];
    const float* db2 = (const float*)d_in[11];
    const float* dw3 = (const float*)d_in[12];
    const float* db3 = (const float*)d_in[13];
    float* out = (float*)d_out;

    const int B = 2048, D = 4096, H1 = 2048, H2 = 1024;

    // Workspace layout (bytes), lifetimes disjoint; peak 40 MB.
    char* ws = (char*)d_ws;
    __bf16* xb   = (__bf16*)(ws);              //  0..16M   x (bf16), dies after enc1
    __bf16* dw3b = (__bf16*)(ws);              //  0..16M   reuses xb region
    __bf16* w1b  = (__bf16*)(ws + 16777216);   // 16..32M   dies after enc1
    float*  h2f  = (float*) (ws + 16777216);   // 16..24M   after enc1
    __bf16* w2b  = (__bf16*)(ws + 25165824);   // 24..28M   dies after enc2
    __bf16* h3b  = (__bf16*)(ws + 25165824);   // 24..28M   after enc2
    __bf16* dw2b = (__bf16*)(ws + 29360128);   // 28..32M
    __bf16* h1b  = (__bf16*)(ws + 33554432);   // 32..40M   dies after enc2
    __bf16* h4b  = (__bf16*)(ws + 33554432);   // 32..40M   after enc2

    dim3 blk(256);

    // casts for enc1 (x, w1): 1048576 + 1048576 groups of 8
    cvt_pair<<<dim3(8192), blk, 0, stream>>>(x, xb, 1048576, w1, w1b);

    // enc1: h1 = relu(x @ w1^T + b1)   [2048x2048x4096]
    gemm_pipe<128, 64, __bf16, true><<<dim3(H1 / 64, B / 128), blk, 49152, stream>>>(
        xb, w1b, b1, h1b, B, H1, D);

    // casts for the rest (w2, dw2, dw3): 262144 + 262144 + 1048576 groups
    cvt_triple<<<dim3(6144), blk, 0, stream>>>(w2, w2b, 262144,
                                               dw2, dw2b, 262144,
                                               dw3, dw3b);

    // enc2: h2 = relu(h1 @ w2^T + b2) -> f32   [2048x1024x2048]
    gemm_pipe<64, 64, float, true><<<dim3(H2 / 64, B / 64), blk, 32768, stream>>>(
        h1b, w2b, b2, h2f, B, H2, H1);

    // enc3 + quantum latent + dec1
    enc3q_dec1<<<dim3(B), blk, 0, stream>>>(h2f, w3, b3, qp, dw1, db1, h3b);

    // dec2: h4 = relu(h3 @ dw2^T + db2)   [2048x2048x1024]
    gemm_pipe<128, 64, __bf16, true><<<dim3(H1 / 64, B / 128), blk, 49152, stream>>>(
        h3b, dw2b, db2, h4b, B, H1, H2);

    // dec3: out = h4 @ dw3^T + db3 -> f32   [2048x4096x2048]
    gemm_pipe<128, 128, float, false><<<dim3(D / 128, B / 128), blk, 65536, stream>>>(
        h4b, dw3b, db3, out, B, D, H1);
}